// Round 10
// baseline (65.037 us; speedup 1.0000x reference)
//
#include <hip/hip_runtime.h>

#define EPSF 0.01f
#define THREADS 256
#define WAVES 4
#define SUB 256                 // elems per wave sub-tile (64 lanes x 4, coalesced)
#define NSUB 16
#define WCH (SUB * NSUB)        // 4096 elems per wave
#define CHUNK (WCH * WAVES)     // 16384 elems per block
#define GSZ (8 * SUB)           // 2048 elems per code group (one uint4/lane)

typedef unsigned long long u64;
typedef unsigned int u32;

// Per-category change scalars, exactly as the reference computes them.
// jnp.clip(x, lo, hi) == min(max(x, lo), hi)
__device__ __forceinline__ void load_changes(const float* bd, const float* de,
                                             const float* sa, const float* in,
                                             const float* bi, float ch[5]) {
    float vbd = *bd, vd = *de, vs = *sa, vi = *in, vbi = *bi;
    ch[0] = fminf(vbd, fminf(0.0f, vd) - EPSF);
    ch[1] = fminf(fmaxf(vd, vbd + EPSF), 0.0f - EPSF);
    ch[2] = fminf(fmaxf(vs, vd + EPSF), vi - EPSF);
    ch[3] = fminf(fmaxf(vi, 0.0f + EPSF), vbi - EPSF);
    ch[4] = fmaxf(vbi, fmaxf(0.0f, vi) + EPSF);
}

// code 0..4 -> change; cmp+cndmask chain (no runtime-indexed array).
__device__ __forceinline__ float selc(u32 v, float c0, float c1, float c2,
                                      float c3, float c4) {
    return (v == 0) ? c0 : (v == 1) ? c1 : (v == 2) ? c2 : (v == 3) ? c3 : c4;
}

// Pass 1 (wave-autonomous, 1 barrier): wave g owns [g*4096, +4096).
// Coalesced int4 reads (1 KB/wave-instr); packs 4-bit codes into 2 uint4/lane
// written coalesced (1 KB/wave-instr); exact counts at BOTH wave granularity
// (bcW, for intra-block bases) and block granularity (bcB, for the global
// predecessor sum -- avoids quadratic redundant L2 reads at wave granularity).
__global__ __launch_bounds__(THREADS) void k_pack(const int* __restrict__ ann,
                                                  uint4* __restrict__ c4,
                                                  int* __restrict__ bcB,
                                                  int* __restrict__ bcW,
                                                  long long n, int nb, int nw) {
    const int tid = threadIdx.x, lane = tid & 63, wv = tid >> 6;
    const int gwave = blockIdx.x * WAVES + wv;
    const long long wbase = (long long)gwave * WCH;
    u64 pk = 0ull;

    if (gwave < nw) {
        for (int g = 0; g < 2; ++g) {
            long long gb = wbase + (long long)g * GSZ;
            if (gb >= n) break;  // wave-uniform
            u32 w0 = 0, w1 = 0, w2 = 0, w3 = 0;
#pragma unroll
            for (int tt = 0; tt < 8; ++tt) {
                long long tb = gb + (long long)tt * SUB;
                if (tb >= n) break;  // wave-uniform
                long long i = tb + (long long)lane * 4;
                u32 nib = 0;
                if (i + 4 <= n) {
                    int4 a = *reinterpret_cast<const int4*>(ann + i);
                    u32 cx = (u32)(a.x - 1), cy = (u32)(a.y - 1);
                    u32 cz = (u32)(a.z - 1), cd = (u32)(a.w - 1);
                    pk += (1ull << (cx * 12)) + (1ull << (cy * 12)) +
                          (1ull << (cz * 12)) + (1ull << (cd * 12));
                    nib = cx | (cy << 4) | (cz << 8) | (cd << 12);
                } else {
#pragma unroll
                    for (int j = 0; j < 4; ++j) {
                        if (i + j < n) {
                            u32 c = (u32)(ann[i + j] - 1);
                            pk += (1ull << (c * 12));
                            nib |= c << (4 * j);
                        }
                    }
                }
                u32 sh = (tt & 1) * 16;
                if (tt < 2) w0 |= nib << sh;
                else if (tt < 4) w1 |= nib << sh;
                else if (tt < 6) w2 |= nib << sh;
                else w3 |= nib << sh;
            }
            c4[((long long)gwave * 2 + g) * 64 + lane] =
                make_uint4(w0, w1, w2, w3);
        }
    }

    // exact counts (<=64 per cat per lane -> 12-bit fields safe)
    int cnt[5];
#pragma unroll
    for (int c = 0; c < 5; ++c) cnt[c] = (int)((pk >> (c * 12)) & 0xFFFull);
#pragma unroll
    for (int c = 0; c < 5; ++c) {
        int s = cnt[c];
#pragma unroll
        for (int off = 32; off > 0; off >>= 1) s += __shfl_down(s, off, 64);
        cnt[c] = s;  // lane 0 holds wave total
    }
    __shared__ int sred[WAVES][5];
    if (lane == 0) {
#pragma unroll
        for (int c = 0; c < 5; ++c) {
            sred[wv][c] = cnt[c];
            if (gwave < nw) bcW[c * nw + gwave] = cnt[c];
        }
    }
    __syncthreads();
    if (tid == 0) {
#pragma unroll
        for (int c = 0; c < 5; ++c)
            bcB[c * nb + blockIdx.x] =
                sred[0][c] + sred[1][c] + sred[2][c] + sred[3][c];
    }
}

// Pass 2 (2 barriers total, hot loop barrier/LDS-free): block-level exact base
// via redundant predecessor-count sum (R9-proven), + <=3 intra-block wave
// counts -> per-wave base; then each wave autonomously decodes its codes from
// registers, wave-scans, emits coalesced float4 exclusive prefixes, chaining
// the carry in-register via __shfl broadcast.
__global__ __launch_bounds__(THREADS) void k_emit(
    const uint4* __restrict__ c4, const int* __restrict__ bcB,
    const int* __restrict__ bcW, float* __restrict__ out, long long n, int nb,
    int nw, const float* org, const float* bd, const float* de,
    const float* sa, const float* in, const float* bi) {
    float ch[5];
    load_changes(bd, de, sa, in, bi, ch);
    const float c0 = ch[0], c1 = ch[1], c2 = ch[2], c3 = ch[3], c4v = ch[4];

    __shared__ int sred[WAVES][5];
    __shared__ float s_base;

    const int tid = threadIdx.x, lane = tid & 63, wv = tid >> 6;
    const int vbid = blockIdx.x;

    // Phase A: block base = org + sum_c (#cat_c in blocks < vbid) * ch_c
    int pc[5];
#pragma unroll
    for (int c = 0; c < 5; ++c) {
        int s = 0;
        for (int j = tid; j < vbid; j += THREADS) s += bcB[c * nb + j];
#pragma unroll
        for (int off = 32; off > 0; off >>= 1) s += __shfl_down(s, off, 64);
        pc[c] = s;
    }
    if (lane == 0) {
#pragma unroll
        for (int c = 0; c < 5; ++c) sred[wv][c] = pc[c];
    }
    __syncthreads();
    if (tid == 0) {
        double acc = (double)(*org);
#pragma unroll
        for (int c = 0; c < 5; ++c) {
            int tot = sred[0][c] + sred[1][c] + sred[2][c] + sred[3][c];
            acc += (double)tot * (double)ch[c];
        }
        s_base = (float)acc;
    }
    __syncthreads();  // last barrier; safe to diverge/return below

    const int gwave = vbid * WAVES + wv;
    if (gwave >= nw) return;

    // per-wave base: add intra-block predecessor waves (<=3 entries x 5 cats;
    // same-address broadcast loads across lanes)
    float running = s_base;
    const int fw = vbid * WAVES;
    for (int j = fw; j < gwave; ++j) {
        running += (float)bcW[0 * nw + j] * c0 + (float)bcW[1 * nw + j] * c1 +
                   (float)bcW[2 * nw + j] * c2 + (float)bcW[3 * nw + j] * c3 +
                   (float)bcW[4 * nw + j] * c4v;
    }

    const long long wbase = (long long)gwave * WCH;
    for (int g = 0; g < 2; ++g) {
        long long gb = wbase + (long long)g * GSZ;
        if (gb >= n) break;  // wave-uniform
        uint4 cv = c4[((long long)gwave * 2 + g) * 64 + lane];
#pragma unroll
        for (int tt = 0; tt < 8; ++tt) {
            long long tb = gb + (long long)tt * SUB;
            if (tb >= n) break;  // wave-uniform
            long long i = tb + (long long)lane * 4;

            u32 w = (tt < 2) ? cv.x : (tt < 4) ? cv.y : (tt < 6) ? cv.z : cv.w;
            u32 nib = w >> ((tt & 1) * 16);
            const bool vec = (i + 4 <= n);
            float d0 = selc(nib & 0xF, c0, c1, c2, c3, c4v);
            float d1 = selc((nib >> 4) & 0xF, c0, c1, c2, c3, c4v);
            float d2 = selc((nib >> 8) & 0xF, c0, c1, c2, c3, c4v);
            float d3 = selc((nib >> 12) & 0xF, c0, c1, c2, c3, c4v);
            if (!vec) {  // partial sub-tile: zero OOB contributions
                if (i + 0 >= n) d0 = 0.0f;
                if (i + 1 >= n) d1 = 0.0f;
                if (i + 2 >= n) d2 = 0.0f;
                if (i + 3 >= n) d3 = 0.0f;
            }
            float e1 = d0, e2 = e1 + d1, e3 = e2 + d2, s = e3 + d3;

            // wave inclusive scan of per-lane sums
            float x = s;
#pragma unroll
            for (int off = 1; off < 64; off <<= 1) {
                float y = __shfl_up(x, off, 64);
                if (lane >= off) x += y;
            }

            float b = running + (x - s);  // exclusive prefix at i
            if (vec) {
                *reinterpret_cast<float4*>(out + i) =
                    make_float4(b, b + e1, b + e2, b + e3);
            } else {
                if (i + 0 < n) out[i + 0] = b;
                if (i + 1 < n) out[i + 1] = b + e1;
                if (i + 2 < n) out[i + 2] = b + e2;
                if (i + 3 < n) out[i + 3] = b + e3;
            }
            running += __shfl(x, 63, 64);  // carry chain, in-register
        }
    }
    if (gwave == nw - 1 && lane == 0) out[n] = running;
}

extern "C" void kernel_launch(void* const* d_in, const int* in_sizes, int n_in,
                              void* d_out, int out_size, void* d_ws, size_t ws_size,
                              hipStream_t stream) {
    const int* ann = (const int*)d_in[0];
    const float* org = (const float*)d_in[1];
    const float* bd = (const float*)d_in[2];
    const float* de = (const float*)d_in[3];
    const float* sa = (const float*)d_in[4];
    const float* in = (const float*)d_in[5];
    const float* bi = (const float*)d_in[6];
    float* out = (float*)d_out;

    long long n = (long long)in_sizes[0];
    int nw = (int)((n + WCH - 1) / WCH);      // 8192 for N=2^25
    if (nw < 1) nw = 1;
    int nb = (nw + WAVES - 1) / WAVES;        // 2048 for N=2^25

    // ws layout: bcB (nb*5) | bcW (nw*5) | codes (nw*2*64 uint4), 256B-aligned
    char* p = (char*)d_ws;
    int* bcB = (int*)p;
    p += ((size_t)nb * 5 * sizeof(int) + 255) & ~(size_t)255;
    int* bcW = (int*)p;
    p += ((size_t)nw * 5 * sizeof(int) + 255) & ~(size_t)255;
    uint4* c4 = (uint4*)p;

    k_pack<<<nb, THREADS, 0, stream>>>(ann, c4, bcB, bcW, n, nb, nw);
    k_emit<<<nb, THREADS, 0, stream>>>(c4, bcB, bcW, out, n, nb, nw, org, bd,
                                       de, sa, in, bi);
}